// Round 10
// baseline (21.392 us; speedup 1.0000x reference)
//
#include <hip/hip_runtime.h>

#define B_    1024
#define NIN_  126
#define NOUT_ 126
#define K_    3
#define H1_   256
#define H2_   256
#define RPB   2
#define TPB   512            // grid 512 -> 2 blocks/CU, 16 waves/CU, 4/SIMD

// bf16 weight copies in d_ws (elements)
#define W0BF_OFF 0           // [256][128] padded, cols 126/127 = 0
#define W1BF_OFF 32768       // [256][256]
#define W2BF_OFF 98304       // [126][256]
#define WBF_TOTAL 130560

__device__ __forceinline__ float elu1(float v) { return v > 0.0f ? v : expm1f(v); }

template<int CTRL>
__device__ __forceinline__ float dpp_add(float v) {
    int s = __builtin_amdgcn_update_dpp(0, __float_as_int(v), CTRL, 0xF, 0xF, true);
    return v + __int_as_float(s);
}
// sum over 8 consecutive lanes: xor1,xor2 via DPP, xor4 via ds_swizzle
__device__ __forceinline__ float qsum8(float v) {
    v = dpp_add<0xB1>(v);
    v = dpp_add<0x4E>(v);
    int s = __builtin_amdgcn_ds_swizzle(__float_as_int(v), 0x101F);
    return v + __int_as_float(s);
}
// static 8-way select without runtime indexing
__device__ __forceinline__ float sel8(int q, float a0, float a1, float a2, float a3,
                                      float a4, float a5, float a6, float a7) {
    float v = a0;
    v = (q == 1) ? a1 : v;  v = (q == 2) ? a2 : v;  v = (q == 3) ? a3 : v;
    v = (q == 4) ? a4 : v;  v = (q == 5) ? a5 : v;  v = (q == 6) ? a6 : v;
    v = (q == 7) ? a7 : v;
    return v;
}
// barrier draining only LDS ops; global loads stay in flight
__device__ __forceinline__ void barrier_lds() {
    asm volatile("s_waitcnt lgkmcnt(0)\n\ts_barrier" ::: "memory");
}
__device__ __forceinline__ unsigned short f2bf(float f) {
    unsigned u = __float_as_uint(f);
    u = (u + 0x7FFFu + ((u >> 16) & 1u)) >> 16;
    return (unsigned short)u;
}
__device__ __forceinline__ float2 bf2f(unsigned u) {
    return make_float2(__uint_as_float(u << 16), __uint_as_float(u & 0xFFFF0000u));
}

// ===================== K1: convert weights to bf16 in d_ws =====================
__global__ __launch_bounds__(256) void wconv(
    const float* __restrict__ W0, const float* __restrict__ W1,
    const float* __restrict__ W2, unsigned short* __restrict__ wsb)
{
    const int t = blockIdx.x * 256 + threadIdx.x;   // grid 512 -> 131072 threads
    if (t < 32768) {                                // W0 padded [256][128]
        const int o = t >> 7, j = t & 127;
        wsb[W0BF_OFF + t] = (j < NIN_) ? f2bf(W0[o * NIN_ + j]) : (unsigned short)0;
    } else if (t < 98304) {                         // W1 [256][256]
        wsb[W1BF_OFF + (t - 32768)] = f2bf(W1[t - 32768]);
    } else if (t < WBF_TOTAL) {                     // W2 [126][256]
        wsb[W2BF_OFF + (t - 98304)] = f2bf(W2[t - 98304]);
    }
}

// ===================== K2: fused MLP, 2 blocks/CU =====================
__global__ __launch_bounds__(TPB, 4) void bim_fused(
    const float* __restrict__ x,  const unsigned short* __restrict__ wsb,
    const float* __restrict__ b0, const float* __restrict__ b1,
    const float* __restrict__ b2, const int* __restrict__ iidx,
    const int* __restrict__ oidx, float* __restrict__ out)
{
    __shared__ float xe [RPB][128];   // scattered x; cols 126/127 stay 0
    __shared__ float h1s[RPB][H1_];
    __shared__ float h2s[RPB][H2_];
    __shared__ float ts [RPB][128];   // b2 folded; cols 126/127 zeroed

    const int tid  = threadIdx.x;
    const int row0 = blockIdx.x * RPB;
    const int q    = tid & 7;    // k-split lane
    const int g    = tid >> 3;   // group 0..63 -> neurons 4g..4g+3

    // ---- phase-A operands (earliest consumers) ----
    int aj0, ar0, aj1, ar1; float ax0, ax1;
    {
        const int n0 = tid;
        ar0 = n0 / (NIN_ * K_); const int m0 = n0 - ar0 * (NIN_ * K_);
        aj0 = iidx[(row0 + ar0) * (NIN_ * K_) + m0];
        ax0 = x[(row0 + ar0) * NIN_ + m0 / K_];
        const int n1 = tid + TPB;
        const bool v1 = n1 < RPB * NIN_ * K_;          // 756 items
        const int n1c = v1 ? n1 : 0;
        ar1 = n1c / (NIN_ * K_); const int m1 = n1c - ar1 * (NIN_ * K_);
        aj1 = iidx[(row0 + ar1) * (NIN_ * K_) + m1];
        ax1 = x[(row0 + ar1) * NIN_ + m1 / K_];
        if (!v1) aj1 = NIN_;
    }

    // ---- W0 full (32 packed VGPRs): consumed in B, covered by A ----
    const unsigned short* w0b = wsb + W0BF_OFF + (g * 4) * 128 + q * 4;
    uint2 wb[4][4];   // [jj][oo]
    #pragma unroll
    for (int jj = 0; jj < 4; ++jj)
        #pragma unroll
        for (int oo = 0; oo < 4; ++oo)
            wb[jj][oo] = *reinterpret_cast<const uint2*>(w0b + oo * 128 + jj * 32);

    // ---- phase-C jj0/jj1 prefetch (16 VGPRs) ----
    const unsigned short* wcp = wsb + W1BF_OFF + (g * 4) * H1_ + q * 4;
    uint2 c0[4], c1[4];
    #pragma unroll
    for (int oo = 0; oo < 4; ++oo) c0[oo] = *reinterpret_cast<const uint2*>(wcp + oo * H1_);
    #pragma unroll
    for (int oo = 0; oo < 4; ++oo) c1[oo] = *reinterpret_cast<const uint2*>(wcp + oo * H1_ + 32);

    // ---- small tail prefetches ----
    const float4 b0v = *reinterpret_cast<const float4*>(b0 + g * 4);
    const float4 b1v = *reinterpret_cast<const float4*>(b1 + g * 4);
    const int    gD  = (g < 63) ? g : 0;
    const float2 b2v = *reinterpret_cast<const float2*>(b2 + gD * 2);
    int ej0, ej1, ej2;
    {
        const int t = tid < RPB * NOUT_ ? tid : 0;
        const int r = t / NOUT_, o = t - r * NOUT_;
        const int base = (row0 + r) * (NOUT_ * K_) + o * K_;
        ej0 = oidx[base]; ej1 = oidx[base + 1]; ej2 = oidx[base + 2];
    }

    // ======== phase A: zero xe, barrier, scatter ========
    if (tid < RPB * 128) (&xe[0][0])[tid] = 0.0f;
    barrier_lds();
    if (aj0 < NIN_) atomicAdd(&xe[ar0][aj0], ax0);
    if (aj1 < NIN_) atomicAdd(&xe[ar1][aj1], ax1);
    barrier_lds();

    // FMA step macros (all indices compile-time)
#define BSTEP(JJ) { \
        const float4 a0 = *reinterpret_cast<const float4*>(&xe[0][q * 4 + (JJ) * 32]); \
        const float4 a1 = *reinterpret_cast<const float4*>(&xe[1][q * 4 + (JJ) * 32]); \
        _Pragma("unroll") \
        for (int oo = 0; oo < 4; ++oo) { \
            const float2 p0 = bf2f(wb[JJ][oo].x); \
            const float2 p1 = bf2f(wb[JJ][oo].y); \
            acc[oo][0] = fmaf(p0.x, a0.x, acc[oo][0]); acc[oo][0] = fmaf(p0.y, a0.y, acc[oo][0]); \
            acc[oo][0] = fmaf(p1.x, a0.z, acc[oo][0]); acc[oo][0] = fmaf(p1.y, a0.w, acc[oo][0]); \
            acc[oo][1] = fmaf(p0.x, a1.x, acc[oo][1]); acc[oo][1] = fmaf(p0.y, a1.y, acc[oo][1]); \
            acc[oo][1] = fmaf(p1.x, a1.z, acc[oo][1]); acc[oo][1] = fmaf(p1.y, a1.w, acc[oo][1]); \
        } }
#define CSTEP(W, JJ) { \
        const float4 a0 = *reinterpret_cast<const float4*>(&h1s[0][q * 4 + (JJ) * 32]); \
        const float4 a1 = *reinterpret_cast<const float4*>(&h1s[1][q * 4 + (JJ) * 32]); \
        _Pragma("unroll") \
        for (int oo = 0; oo < 4; ++oo) { \
            const float2 p0 = bf2f(W[oo].x); \
            const float2 p1 = bf2f(W[oo].y); \
            acc[oo][0] = fmaf(p0.x, a0.x, acc[oo][0]); acc[oo][0] = fmaf(p0.y, a0.y, acc[oo][0]); \
            acc[oo][0] = fmaf(p1.x, a0.z, acc[oo][0]); acc[oo][0] = fmaf(p1.y, a0.w, acc[oo][0]); \
            acc[oo][1] = fmaf(p0.x, a1.x, acc[oo][1]); acc[oo][1] = fmaf(p0.y, a1.y, acc[oo][1]); \
            acc[oo][1] = fmaf(p1.x, a1.z, acc[oo][1]); acc[oo][1] = fmaf(p1.y, a1.w, acc[oo][1]); \
        } }
#define DSTEP(W, JJ) { \
        const float4 a0 = *reinterpret_cast<const float4*>(&h2s[0][q * 4 + (JJ) * 32]); \
        const float4 a1 = *reinterpret_cast<const float4*>(&h2s[1][q * 4 + (JJ) * 32]); \
        _Pragma("unroll") \
        for (int oo = 0; oo < 2; ++oo) { \
            const float2 p0 = bf2f(W[oo].x); \
            const float2 p1 = bf2f(W[oo].y); \
            accd[oo][0] = fmaf(p0.x, a0.x, accd[oo][0]); accd[oo][0] = fmaf(p0.y, a0.y, accd[oo][0]); \
            accd[oo][0] = fmaf(p1.x, a0.z, accd[oo][0]); accd[oo][0] = fmaf(p1.y, a0.w, accd[oo][0]); \
            accd[oo][1] = fmaf(p0.x, a1.x, accd[oo][1]); accd[oo][1] = fmaf(p0.y, a1.y, accd[oo][1]); \
            accd[oo][1] = fmaf(p1.x, a1.z, accd[oo][1]); accd[oo][1] = fmaf(p1.y, a1.w, accd[oo][1]); \
        } }
#define ISSUE_C(DST, JJ) { _Pragma("unroll") \
        for (int oo = 0; oo < 4; ++oo) DST[oo] = *reinterpret_cast<const uint2*>(wcp + oo * H1_ + (JJ) * 32); }
#define ISSUE_D(DST, JJ) { _Pragma("unroll") \
        for (int oo = 0; oo < 2; ++oo) DST[oo] = *reinterpret_cast<const uint2*>(wdp + oo * H2_ + (JJ) * 32); }

    // ======== phase B: h1 = elu(xe @ W0^T + b0); stream c2,c3 ========
    uint2 c2[4], c3[4];
    {
        float acc[4][2] = {};
        BSTEP(0)
        ISSUE_C(c2, 2)
        BSTEP(1)
        ISSUE_C(c3, 3)
        BSTEP(2)
        BSTEP(3)
        #pragma unroll
        for (int oo = 0; oo < 4; ++oo)
            #pragma unroll
            for (int r = 0; r < RPB; ++r) acc[oo][r] = qsum8(acc[oo][r]);
        // flat = oo*2 + r = q
        const float v = sel8(q, acc[0][0], acc[0][1], acc[1][0], acc[1][1],
                                acc[2][0], acc[2][1], acc[3][0], acc[3][1]);
        const int oo = q >> 1, r = q & 1;
        const float bias = (oo == 0) ? b0v.x : (oo == 1) ? b0v.y : (oo == 2) ? b0v.z : b0v.w;
        h1s[r][g * 4 + oo] = elu1(v + bias);
    }
    barrier_lds();

    // ======== phase C: h2 = elu(h1 @ W1^T + b1); stream c4..c7, d0,d1 ====
    const unsigned short* wdp = wsb + W2BF_OFF + (gD * 2) * H2_ + q * 4;
    uint2 c4[4], c5[4], c6[4], c7[4], d0[2], d1[2];
    {
        float acc[4][2] = {};
        CSTEP(c0, 0)
        ISSUE_C(c4, 4)
        CSTEP(c1, 1)
        ISSUE_C(c5, 5)
        CSTEP(c2, 2)
        ISSUE_C(c6, 6)
        CSTEP(c3, 3)
        ISSUE_C(c7, 7)
        CSTEP(c4, 4)
        ISSUE_D(d0, 0)
        CSTEP(c5, 5)
        ISSUE_D(d1, 1)
        CSTEP(c6, 6)
        CSTEP(c7, 7)
        #pragma unroll
        for (int oo = 0; oo < 4; ++oo)
            #pragma unroll
            for (int r = 0; r < RPB; ++r) acc[oo][r] = qsum8(acc[oo][r]);
        const float v = sel8(q, acc[0][0], acc[0][1], acc[1][0], acc[1][1],
                                acc[2][0], acc[2][1], acc[3][0], acc[3][1]);
        const int oo = q >> 1, r = q & 1;
        const float bias = (oo == 0) ? b1v.x : (oo == 1) ? b1v.y : (oo == 2) ? b1v.z : b1v.w;
        h2s[r][g * 4 + oo] = elu1(v + bias);
    }
    barrier_lds();

    // ======== phase D: ts[r][j] = h2s[r].W2[j,:] + b2[j]; stream d2..d7 ===
    {
        uint2 d2[2], d3[2], d4[2], d5[2], d6[2], d7[2];
        float accd[2][2] = {};
        DSTEP(d0, 0)
        ISSUE_D(d2, 2)
        DSTEP(d1, 1)
        ISSUE_D(d3, 3)
        DSTEP(d2, 2)
        ISSUE_D(d4, 4)
        DSTEP(d3, 3)
        ISSUE_D(d5, 5)
        DSTEP(d4, 4)
        ISSUE_D(d6, 6)
        DSTEP(d5, 5)
        ISSUE_D(d7, 7)
        DSTEP(d6, 6)
        DSTEP(d7, 7)
        #pragma unroll
        for (int oo = 0; oo < 2; ++oo)
            #pragma unroll
            for (int r = 0; r < RPB; ++r) accd[oo][r] = qsum8(accd[oo][r]);
        // flat = oo*2 + r = q (q<4)
        const float v = sel8(q, accd[0][0], accd[0][1], accd[1][0], accd[1][1],
                                accd[0][0], accd[0][1], accd[1][0], accd[1][1]);
        if (q < 4) {
            const int oo = q >> 1, rr = q & 1;
            if (g < 63) ts[rr][g * 2 + oo] = v + (oo ? b2v.y : b2v.x);
            else        ts[rr][126 + oo]   = 0.0f;
        }
    }
    barrier_lds();

    // ======== phase E: out[b,o] = sum_k ts[r][ej_k] (b2 folded) ========
    if (tid < RPB * NOUT_) {
        const int r = tid / NOUT_, o = tid - r * NOUT_;
        out[(row0 + r) * NOUT_ + o] = ts[r][ej0] + ts[r][ej1] + ts[r][ej2];
    }
#undef BSTEP
#undef CSTEP
#undef DSTEP
#undef ISSUE_C
#undef ISSUE_D
}

extern "C" void kernel_launch(void* const* d_in, const int* in_sizes, int n_in,
                              void* d_out, int out_size, void* d_ws, size_t ws_size,
                              hipStream_t stream) {
    const float* x   = (const float*)d_in[0];
    const float* W0  = (const float*)d_in[1];
    const float* b0  = (const float*)d_in[2];
    const float* W1  = (const float*)d_in[3];
    const float* b1  = (const float*)d_in[4];
    const float* W2  = (const float*)d_in[5];
    const float* b2  = (const float*)d_in[6];
    const int*  iidx = (const int*)d_in[7];
    const int*  oidx = (const int*)d_in[8];
    float* out = (float*)d_out;
    unsigned short* wsb = (unsigned short*)d_ws;

    wconv<<<512, 256, 0, stream>>>(W0, W1, W2, wsb);
    bim_fused<<<B_ / RPB, TPB, 0, stream>>>(x, wsb, b0, b1, b2, iidx, oidx, out);
}